// Round 2
// baseline (2051.770 us; speedup 1.0000x reference)
//
#include <hip/hip_runtime.h>
#include <math.h>
#include <stdint.h>

// Problem constants
#define B_ 512
#define D_ 1024
#define H_ 1024
#define T_ 48
#define NG 4096      // 4*H gate columns
#define K2 2048      // D + H concatenated K for the per-step GEMM

typedef _Float16 half8 __attribute__((ext_vector_type(8)));
typedef float f32x4 __attribute__((ext_vector_type(4)));

// Async global->LDS, 16B per lane. LDS dest must be wave-uniform base; HW adds lane*16.
__device__ __forceinline__ void cp16(const void* g, void* l) {
  __builtin_amdgcn_global_load_lds(
      (__attribute__((address_space(1))) const unsigned int*)(uintptr_t)g,
      (__attribute__((address_space(3))) unsigned int*)(uintptr_t)l, 16, 0, 0);
}

__device__ __forceinline__ float sigmoidf_(float x) { return 1.0f / (1.0f + expf(-x)); }

// ---------------------------------------------------------------------------
// Prep: W_cat[j][0:1024]=W_ih[j][0:1024], W_cat[j][1024:2048]=W_hh[j][:]  (f16)
//       Wp[j][k] = W_ih[j][1024+k]                                        (f16)
// ---------------------------------------------------------------------------
__global__ void prep_w(const float* __restrict__ W_ih, const float* __restrict__ W_hh,
                       _Float16* __restrict__ Wcat, _Float16* __restrict__ Wp) {
  int idx = blockIdx.x * 256 + threadIdx.x;
  const int n1 = NG * K2;  // 8388608
  if (idx < n1) {
    int j = idx >> 11, k = idx & 2047;
    float v = (k < D_) ? W_ih[j * K2 + k] : W_hh[j * H_ + (k - D_)];
    Wcat[idx] = (_Float16)v;
  } else {
    int i2 = idx - n1;
    if (i2 < NG * D_) {
      int j = i2 >> 10, k = i2 & 1023;
      Wp[i2] = (_Float16)W_ih[j * K2 + D_ + k];
    }
  }
}

// ---------------------------------------------------------------------------
// Pool: pooled[b][d] = sum_t mask(t,b)*dh[t][b][d] / sum_t mask(t,b); also dh->f16 (t>=1)
// ---------------------------------------------------------------------------
__global__ void pool_conv(const float* __restrict__ dh, const int* __restrict__ caps,
                          _Float16* __restrict__ dh16, _Float16* __restrict__ pooled16) {
  int tid = blockIdx.x * 256 + threadIdx.x;  // b*1024 + d, < 524288
  int b = tid >> 10;
  float sum = 0.0f, cnt = 0.0f;
  for (int t = 0; t < T_; ++t) {
    int cap = caps[t * B_ + b];
    float v = dh[(size_t)t * (B_ * D_) + tid];
    if (cap != 0 && cap != 2) { sum += v; cnt += 1.0f; }
    if (t >= 1) dh16[(size_t)t * (B_ * D_) + tid] = (_Float16)v;
  }
  pooled16[tid] = (_Float16)(sum / cnt);
}

// ---------------------------------------------------------------------------
// Init: hA=0, c=0, feats[:,0,:]=0
// ---------------------------------------------------------------------------
__global__ void init_zero(_Float16* __restrict__ hA, float* __restrict__ c,
                          float* __restrict__ out) {
  int tid = blockIdx.x * 256 + threadIdx.x;  // < 524288
  hA[tid] = (_Float16)0.0f;
  c[tid] = 0.0f;
  int b = tid >> 10, d = tid & 1023;
  out[(size_t)b * (T_ * H_) + d] = 0.0f;
}

// ---------------------------------------------------------------------------
// Xc[b][n] = sum_k pooled[b][k]*Wp[n][k] + b_ih[n] + b_hh[n]
// 64x128 tile, 4 waves in 2x2, each wave 32x64 (2 m-tiles x 4 n-tiles of 16x16)
// ---------------------------------------------------------------------------
__global__ __launch_bounds__(256) void gemm_pool(
    const _Float16* __restrict__ A, const _Float16* __restrict__ Wp,
    const float* __restrict__ b_ih, const float* __restrict__ b_hh,
    float* __restrict__ Xc) {
  __shared__ __align__(16) _Float16 sA[64 * 32];
  __shared__ __align__(16) _Float16 sB[128 * 32];
  const int tid = threadIdx.x;
  const int wave = tid >> 6, lane = tid & 63;
  const int quad = lane >> 4, l16 = lane & 15;
  const int wm = wave & 1, wn = wave >> 1;
  const int n0 = blockIdx.x * 128;
  const int b0 = blockIdx.y * 64;
  const int rS = tid >> 2, cS = tid & 3;

  f32x4 acc[2][4] = {};
  for (int k0 = 0; k0 < 1024; k0 += 32) {
    cp16(A + (size_t)(b0 + rS) * 1024 + k0 + cS * 8, sA + wave * 512);
    cp16(Wp + (size_t)(n0 + rS) * 1024 + k0 + cS * 8, sB + wave * 512);
    cp16(Wp + (size_t)(n0 + 64 + rS) * 1024 + k0 + cS * 8, sB + 2048 + wave * 512);
    __syncthreads();
    half8 a[2], bfr[4];
#pragma unroll
    for (int m = 0; m < 2; ++m)
      a[m] = *(const half8*)(sA + (wm * 32 + m * 16 + l16) * 32 + quad * 8);
#pragma unroll
    for (int n = 0; n < 4; ++n)
      bfr[n] = *(const half8*)(sB + (wn * 64 + n * 16 + l16) * 32 + quad * 8);
#pragma unroll
    for (int m = 0; m < 2; ++m)
#pragma unroll
      for (int n = 0; n < 4; ++n)
        acc[m][n] = __builtin_amdgcn_mfma_f32_16x16x32_f16(a[m], bfr[n], acc[m][n], 0, 0, 0);
    __syncthreads();
  }
#pragma unroll
  for (int m = 0; m < 2; ++m) {
#pragma unroll
    for (int n = 0; n < 4; ++n) {
      int nn = n0 + wn * 64 + n * 16 + l16;
      float bias = b_ih[nn] + b_hh[nn];
#pragma unroll
      for (int r = 0; r < 4; ++r) {
        int bb = b0 + wm * 32 + m * 16 + quad * 4 + r;
        Xc[(size_t)bb * NG + nn] = acc[m][n][r] + bias;
      }
    }
  }
}

// ---------------------------------------------------------------------------
// One LSTM step: gates = [dh_t | h_prev] @ [Wx | Whh]^T + Xc, then cell update.
// h is ping-ponged across launches: reads h_prev, writes h_next (fixes the
// cross-block read/write race on a single h buffer).
// Block tile: M=64 batch rows x 128 gate-cols (4 gates x 32 hidden cols,
// interleaved so each wave's 4 n-tiles are exactly gates i,f,g,o).
// ---------------------------------------------------------------------------
__global__ __launch_bounds__(256) void lstm_step(
    const _Float16* __restrict__ dh16, const _Float16* __restrict__ Wcat,
    const float* __restrict__ Xc, const _Float16* __restrict__ h_prev,
    _Float16* __restrict__ h_next, float* __restrict__ c,
    float* __restrict__ out, int t) {
  __shared__ __align__(16) _Float16 sA[64 * 32];
  __shared__ __align__(16) _Float16 sB[128 * 32];
  const int tid = threadIdx.x;
  const int wave = tid >> 6, lane = tid & 63;
  const int quad = lane >> 4, l16 = lane & 15;
  const int wm = wave & 1, wn = wave >> 1;
  const int j0 = blockIdx.x * 32;   // hidden-col group
  const int b0 = blockIdx.y * 64;   // batch rows
  const int rS = tid >> 2, cS = tid & 3;

  const _Float16* dhT = dh16 + (size_t)t * (B_ * D_);
  const int jr0 = (((rS >> 4) & 3) << 10) + j0 + (rS & 15);  // B-rows 0..63
  const int jr1 = jr0 + 16;                                  // B-rows 64..127
  const int aRow = b0 + rS;

  f32x4 acc[2][4] = {};
  for (int k0 = 0; k0 < K2; k0 += 32) {
    const _Float16* aSrc = (k0 < 1024)
        ? (dhT + (size_t)aRow * 1024 + k0 + cS * 8)
        : (h_prev + (size_t)aRow * 1024 + (k0 - 1024) + cS * 8);
    cp16(aSrc, sA + wave * 512);
    cp16(Wcat + (size_t)jr0 * K2 + k0 + cS * 8, sB + wave * 512);
    cp16(Wcat + (size_t)jr1 * K2 + k0 + cS * 8, sB + 2048 + wave * 512);
    __syncthreads();
    half8 a[2], bfr[4];
#pragma unroll
    for (int m = 0; m < 2; ++m)
      a[m] = *(const half8*)(sA + (wm * 32 + m * 16 + l16) * 32 + quad * 8);
#pragma unroll
    for (int n = 0; n < 4; ++n)
      bfr[n] = *(const half8*)(sB + (wn * 64 + n * 16 + l16) * 32 + quad * 8);
#pragma unroll
    for (int m = 0; m < 2; ++m)
#pragma unroll
      for (int n = 0; n < 4; ++n)
        acc[m][n] = __builtin_amdgcn_mfma_f32_16x16x32_f16(a[m], bfr[n], acc[m][n], 0, 0, 0);
    __syncthreads();
  }

  // Epilogue: acc[m][0..3] = i,f,g,o for (b = quad*4+reg rows, col = j0+wn*16+l16)
  const int col = j0 + wn * 16 + l16;
#pragma unroll
  for (int m = 0; m < 2; ++m) {
#pragma unroll
    for (int r = 0; r < 4; ++r) {
      int bb = b0 + wm * 32 + m * 16 + quad * 4 + r;
      const float* xb = Xc + (size_t)bb * NG + col;
      float iv = acc[m][0][r] + xb[0];
      float fv = acc[m][1][r] + xb[1024];
      float gv = acc[m][2][r] + xb[2048];
      float ov = acc[m][3][r] + xb[3072];
      float ig = sigmoidf_(iv), fg = sigmoidf_(fv), og = sigmoidf_(ov);
      float gg = tanhf(gv);
      size_t ci = (size_t)bb * H_ + col;
      float cn = fg * c[ci] + ig * gg;
      c[ci] = cn;
      float hv = og * tanhf(cn);
      h_next[ci] = (_Float16)hv;
      out[(size_t)bb * (T_ * H_) + (size_t)t * H_ + col] = hv;
    }
  }
}

// ---------------------------------------------------------------------------
extern "C" void kernel_launch(void* const* d_in, const int* in_sizes, int n_in,
                              void* d_out, int out_size, void* d_ws, size_t ws_size,
                              hipStream_t stream) {
  (void)in_sizes; (void)n_in; (void)out_size; (void)ws_size;
  const float* dh   = (const float*)d_in[0];
  // d_in[1] ("outputs") is unused by the reference
  const int*   caps = (const int*)d_in[2];
  const float* W_ih = (const float*)d_in[3];
  const float* W_hh = (const float*)d_in[4];
  const float* b_ih = (const float*)d_in[5];
  const float* b_hh = (const float*)d_in[6];
  float* out = (float*)d_out;

  char* ws = (char*)d_ws;
  _Float16* Wcat  = (_Float16*)(ws);              // 16,777,216 B
  _Float16* Wp    = (_Float16*)(ws + 16777216);   //  8,388,608 B
  _Float16* dh16  = (_Float16*)(ws + 25165824);   // 50,331,648 B
  _Float16* pld16 = (_Float16*)(ws + 75497472);   //  1,048,576 B
  float*    Xc    = (float*)   (ws + 76546048);   //  8,388,608 B
  _Float16* hA    = (_Float16*)(ws + 84934656);   //  1,048,576 B
  _Float16* hB    = (_Float16*)(ws + 85983232);   //  1,048,576 B
  float*    c     = (float*)   (ws + 87031808);   //  2,097,152 B  (end ~89.1 MB)

  prep_w<<<49152, 256, 0, stream>>>(W_ih, W_hh, Wcat, Wp);
  pool_conv<<<2048, 256, 0, stream>>>(dh, caps, dh16, pld16);
  init_zero<<<2048, 256, 0, stream>>>(hA, c, out);
  gemm_pool<<<dim3(32, 8), 256, 0, stream>>>(pld16, Wp, b_ih, b_hh, Xc);
  for (int t = 1; t < T_; ++t) {
    const _Float16* hp = (t & 1) ? hA : hB;
    _Float16*       hn = (t & 1) ? hB : hA;
    lstm_step<<<dim3(32, 8), 256, 0, stream>>>(dh16, Wcat, Xc, hp, hn, c, out, t);
  }
}